// Round 3
// baseline (222.054 us; speedup 1.0000x reference)
//
#include <hip/hip_runtime.h>
#include <math.h>

#define T_LEN 4096
#define CHUNK 8
#define NTHR  512
#define NWAVE (NTHR / 64)
#define DT    (1.0f / 200.0f)

// Rodrigues rotation for axis-angle w*dt. theta = |w|*dt <= ~0.05 for this
// problem, so degree-5/6 Taylor for sin/(1-cos) is exact to fp32 (rel err
// <1e-10), replacing libm sinf/cosf range-reduction calls.
__device__ __forceinline__ void make_A(float wx, float wy, float wz, float* A) {
    float nsq   = wx*wx + wy*wy + wz*wz;
    float n     = sqrtf(nsq);
    float theta = n * DT;
    float inv   = 1.0f / (n + 1e-8f);
    float x = wx*inv, y = wy*inv, z = wz*inv;
    float t2 = theta * theta;
    float s  = theta * (1.0f - t2 * (1.0f/6.0f)  * (1.0f - t2 * (1.0f/20.0f)));
    float oc = t2 * 0.5f * (1.0f - t2 * (1.0f/12.0f) * (1.0f - t2 * (1.0f/30.0f)));
    A[0] = 1.0f + oc * (-(y*y + z*z));
    A[1] = -s*z + oc * (x*y);
    A[2] =  s*y + oc * (x*z);
    A[3] =  s*z + oc * (x*y);
    A[4] = 1.0f + oc * (-(x*x + z*z));
    A[5] = -s*x + oc * (y*z);
    A[6] = -s*y + oc * (x*z);
    A[7] =  s*x + oc * (y*z);
    A[8] = 1.0f + oc * (-(x*x + y*y));
}

__device__ __forceinline__ void matmul3(const float* R, const float* A, float* N) {
#pragma unroll
    for (int i = 0; i < 3; ++i) {
        N[i*3+0] = R[i*3+0]*A[0] + R[i*3+1]*A[3] + R[i*3+2]*A[6];
        N[i*3+1] = R[i*3+0]*A[1] + R[i*3+1]*A[4] + R[i*3+2]*A[7];
        N[i*3+2] = R[i*3+0]*A[2] + R[i*3+1]*A[5] + R[i*3+2]*A[8];
    }
}

// One reference step applied to state (R, v, p).
__device__ __forceinline__ void step(float* R, float* v, float* p,
                                     float wx, float wy, float wz,
                                     float ax, float ay, float az) {
    const float dt2h = DT * DT * 0.5f;
    float A[9], N[9];
    make_A(wx, wy, wz, A);
    matmul3(R, A, N);
#pragma unroll
    for (int i = 0; i < 9; ++i) R[i] = N[i];
    float rax = R[0]*ax + R[1]*ay + R[2]*az;
    float ray = R[3]*ax + R[4]*ay + R[5]*az;
    float raz = R[6]*ax + R[7]*ay + R[8]*az;
    v[0] += rax*DT; v[1] += ray*DT; v[2] += raz*DT;
    p[0] += v[0]*DT + rax*dt2h;
    p[1] += v[1]*DT + ray*dt2h;
    p[2] += v[2]*DT + raz*dt2h;
}

// O = L ∘ R, where L precedes R and R spans tau2 seconds.
// Element = (A[9], b[3], c[3]):  A=L.A@R.A; b=L.b+L.A@R.b; c=L.c+tau2*L.b+L.A@R.c
__device__ __forceinline__ void compose15(const float* L, const float* Rv,
                                          float* O, float tau2) {
    float NA[9];
    matmul3(L, Rv, NA);
    float nb0 = L[9]  + L[0]*Rv[9] + L[1]*Rv[10] + L[2]*Rv[11];
    float nb1 = L[10] + L[3]*Rv[9] + L[4]*Rv[10] + L[5]*Rv[11];
    float nb2 = L[11] + L[6]*Rv[9] + L[7]*Rv[10] + L[8]*Rv[11];
    float nc0 = L[12] + tau2*L[9]  + L[0]*Rv[12] + L[1]*Rv[13] + L[2]*Rv[14];
    float nc1 = L[13] + tau2*L[10] + L[3]*Rv[12] + L[4]*Rv[13] + L[5]*Rv[14];
    float nc2 = L[14] + tau2*L[11] + L[6]*Rv[12] + L[7]*Rv[13] + L[8]*Rv[14];
#pragma unroll
    for (int i = 0; i < 9; ++i) O[i] = NA[i];
    O[9] = nb0; O[10] = nb1; O[11] = nb2;
    O[12] = nc0; O[13] = nc1; O[14] = nc2;
}

__global__ __launch_bounds__(NTHR)
void preint_kernel(const float* __restrict__ in, float* __restrict__ out) {
    const int b    = blockIdx.x;
    const int t    = threadIdx.x;
    const int lane = t & 63;
    const int wid  = t >> 6;

    const float* bin  = in  + (size_t)b * T_LEN * 6;
    float*       bout = out + (size_t)b * T_LEN * 16;
    const float2* cin2 = (const float2*)(bin + (size_t)t * CHUNK * 6);

    // ---- Phase 1: per-thread chunk element (state from identity) ----
    float val[15];
    {
        float R[9] = {1,0,0, 0,1,0, 0,0,1};
        float v[3] = {0,0,0};
        float p[3] = {0,0,0};
#pragma unroll
        for (int k = 0; k < CHUNK; ++k) {
            float2 u0 = cin2[k*3+0];
            float2 u1 = cin2[k*3+1];
            float2 u2 = cin2[k*3+2];
            step(R, v, p, u0.x, u0.y, u1.x, u1.y, u2.x, u2.y);
        }
#pragma unroll
        for (int i = 0; i < 9; ++i) val[i] = R[i];
        val[9]  = v[0]; val[10] = v[1]; val[11] = v[2];
        val[12] = p[0]; val[13] = p[1]; val[14] = p[2];
    }

    // ---- Phase 2a: intra-wave inclusive scan (shuffles, no barriers) ----
#pragma unroll
    for (int d = 1; d < 64; d <<= 1) {
        float L[15];
#pragma unroll
        for (int i = 0; i < 15; ++i) L[i] = __shfl_up(val[i], d, 64);
        if (lane >= d) {
            float O[15];
            compose15(L, val, O, (float)(d * CHUNK) * DT);
#pragma unroll
            for (int i = 0; i < 15; ++i) val[i] = O[i];
        }
    }

    // ---- Phase 2b: cross-wave exchange of wave totals ----
    __shared__ float wtot[NWAVE][16];
    if (lane == 63) {
#pragma unroll
        for (int i = 0; i < 15; ++i) wtot[wid][i] = val[i];
    }
    __syncthreads();

    // Exclusive wave prefix E = wtot[0] ∘ ... ∘ wtot[wid-1]
    float E[15];
    if (wid > 0) {
#pragma unroll
        for (int i = 0; i < 15; ++i) E[i] = wtot[0][i];
        const float tauW = (float)(64 * CHUNK) * DT;
        for (int w = 1; w < wid; ++w) {
            float Tw[15], O[15];
#pragma unroll
            for (int i = 0; i < 15; ++i) Tw[i] = wtot[w][i];
            compose15(E, Tw, O, tauW);
#pragma unroll
            for (int i = 0; i < 15; ++i) E[i] = O[i];
        }
    }

    // Intra-wave exclusive value P (lane-1's inclusive; identity for lane 0)
    float P[15];
#pragma unroll
    for (int i = 0; i < 15; ++i) P[i] = __shfl_up(val[i], 1, 64);
    if (lane == 0) {
        P[0]=1; P[1]=0; P[2]=0; P[3]=0; P[4]=1; P[5]=0; P[6]=0; P[7]=0; P[8]=1;
#pragma unroll
        for (int i = 9; i < 15; ++i) P[i] = 0.0f;
    }

    // Thread's exclusive prefix state X
    float X[15];
    if (wid > 0) {
        compose15(E, P, X, (float)(lane * CHUNK) * DT);
    } else {
#pragma unroll
        for (int i = 0; i < 15; ++i) X[i] = P[i];
    }

    // ---- Phase 3: replay chunk from exclusive-prefix state, emit outputs ----
    float S[9], sv[3], sp[3];
#pragma unroll
    for (int i = 0; i < 9; ++i) S[i] = X[i];
    sv[0] = X[9];  sv[1] = X[10]; sv[2] = X[11];
    sp[0] = X[12]; sp[1] = X[13]; sp[2] = X[14];

    // Emit rows in pairs so each lane writes a full, aligned 128B L2 line.
#pragma unroll
    for (int kk = 0; kk < CHUNK; kk += 2) {
        float4 row[8];
#pragma unroll
        for (int j = 0; j < 2; ++j) {
            const int k = kk + j;
            float2 u0 = cin2[k*3+0];
            float2 u1 = cin2[k*3+1];
            float2 u2 = cin2[k*3+2];
            step(S, sv, sp, u0.x, u0.y, u1.x, u1.y, u2.x, u2.y);

            // quaternion, closed-form (== reference acos/sin path incl. clip):
            float tr  = S[0] + S[4] + S[8];
            float ca  = fminf(fmaxf(0.5f * (tr - 1.0f), -1.0f + 1e-7f), 1.0f - 1e-7f);
            float qw  = sqrtf(0.5f * (1.0f + ca));
            float i4  = 0.25f / qw;
            float qx  = (S[7] - S[5]) * i4;
            float qy  = (S[2] - S[6]) * i4;
            float qz  = (S[3] - S[1]) * i4;

            row[j*4+0] = make_float4(u0.x, u0.y, u1.x, u1.y);
            row[j*4+1] = make_float4(u2.x, u2.y, sp[0], sp[1]);
            row[j*4+2] = make_float4(sp[2], qw, qx, qy);
            row[j*4+3] = make_float4(qz, sv[0], sv[1], sv[2]);
        }
        float4* orow = (float4*)(bout + (size_t)(t * CHUNK + kk) * 16);
#pragma unroll
        for (int i = 0; i < 8; ++i) orow[i] = row[i];
    }
}

extern "C" void kernel_launch(void* const* d_in, const int* in_sizes, int n_in,
                              void* d_out, int out_size, void* d_ws, size_t ws_size,
                              hipStream_t stream) {
    const float* in = (const float*)d_in[0];
    float* out = (float*)d_out;
    const int B = in_sizes[0] / (T_LEN * 6);   // 512
    preint_kernel<<<dim3(B), dim3(NTHR), 0, stream>>>(in, out);
}